// Round 4
// baseline (492.669 us; speedup 1.0000x reference)
//
#include <hip/hip_runtime.h>

#define N_NODES 100000
#define N_EDGES 1600000
#define IN_DIM 128
#define HID 64
#define OUT_DIM 64

__device__ __forceinline__ unsigned bf16r(float f) {   // fp32 -> bf16 bits, RNE
    unsigned u = __float_as_uint(f);
    return (u + 0x7FFFu + ((u >> 16) & 1u)) >> 16;
}
__device__ __forceinline__ float blo(unsigned u) { return __uint_as_float(u << 16); }
__device__ __forceinline__ float bhi(unsigned u) { return __uint_as_float(u & 0xFFFF0000u); }

// ---------------- K1: h2(bf16) = x @ W_lin^T ; s = h@att[:64]; d = h@att[64:] ----
// 64x64 block tile, 4x4 per thread: 2 B LDS-read per lane-FMA (was 3 B).
#define K1_ROWS 64
#define K1PAD 68

__global__ __launch_bounds__(256) void k1_linear(const float* __restrict__ x,
                                                 const float* __restrict__ W,
                                                 const float* __restrict__ att,
                                                 uint2* __restrict__ h2v,
                                                 float* __restrict__ s,
                                                 float* __restrict__ d) {
    __shared__ float xsT[IN_DIM * K1PAD];   // 34,816 B
    __shared__ float wsT[IN_DIM * K1PAD];   // 34,816 B
    __shared__ float satt[2 * HID];
    __shared__ float sacc[K1_ROWS], dacc[K1_ROWS];
    const int tid = threadIdx.x;
    const int row0 = blockIdx.x * K1_ROWS;  // grid 1563, last block partial

    if (tid < 128) satt[tid] = att[tid];
    if (tid < K1_ROWS) { sacc[tid] = 0.f; dacc[tid] = 0.f; }
    for (int i = tid; i < HID * IN_DIM; i += 256) {
        int c = i >> 7, k = i & 127;
        wsT[k * K1PAD + c] = W[i];
    }
    for (int i = tid; i < K1_ROWS * IN_DIM; i += 256) {
        int r = i >> 7, k = i & 127;
        int row = row0 + r;
        xsT[k * K1PAD + r] = (row < N_NODES) ? x[row * IN_DIM + k] : 0.f;
    }
    __syncthreads();

    const int r0 = (tid & 15) * 4;
    const int c0 = (tid >> 4) * 4;
    float acc[4][4] = {};
#pragma unroll 4
    for (int k = 0; k < IN_DIM; ++k) {
        const float4 xv = *(const float4*)&xsT[k * K1PAD + r0];
        const float4 wv = *(const float4*)&wsT[k * K1PAD + c0];
#pragma unroll
        for (int i2 = 0; i2 < 4; ++i2) {
            float xi = (&xv.x)[i2];
            acc[i2][0] += xi * wv.x; acc[i2][1] += xi * wv.y;
            acc[i2][2] += xi * wv.z; acc[i2][3] += xi * wv.w;
        }
    }
#pragma unroll
    for (int i2 = 0; i2 < 4; ++i2) {
        int row = row0 + r0 + i2;
        unsigned p0 = bf16r(acc[i2][0]) | (bf16r(acc[i2][1]) << 16);
        unsigned p1 = bf16r(acc[i2][2]) | (bf16r(acc[i2][3]) << 16);
        if (row < N_NODES) h2v[row * 16 + (c0 >> 2)] = make_uint2(p0, p1);
        float ps = 0.f, pd = 0.f;
#pragma unroll
        for (int j = 0; j < 4; ++j) {
            ps += acc[i2][j] * satt[c0 + j];
            pd += acc[i2][j] * satt[HID + c0 + j];
        }
        atomicAdd(&sacc[r0 + i2], ps);
        atomicAdd(&dacc[r0 + i2], pd);
    }
    __syncthreads();
    if (tid < K1_ROWS) {
        int row = row0 + tid;
        if (row < N_NODES) { s[row] = sacc[tid]; d[row] = dacc[tid]; }
    }
}

// ---------------- K2a: in-degree histogram (int4, 4 edges/thread) -----------
__global__ __launch_bounds__(256) void k2a_count(const int* __restrict__ ei,
                                                 int* __restrict__ counts) {
    int i = blockIdx.x * 256 + threadIdx.x;   // grid 1563, guard
    if (i >= N_EDGES / 4) return;
    int4 dv = ((const int4*)(ei + N_EDGES))[i];
    atomicAdd(&counts[dv.x], 1);
    atomicAdd(&counts[dv.y], 1);
    atomicAdd(&counts[dv.z], 1);
    atomicAdd(&counts[dv.w], 1);
}

// ---------------- scan: exclusive prefix over counts (int4-vectorized) -------
#define SCAN_V4 (N_NODES / 4)   // 25000, exact
__global__ __launch_bounds__(1024) void k_scan(const int* __restrict__ counts,
                                               int* __restrict__ row_start,
                                               int* __restrict__ cursor) {
    __shared__ int wsum[16];
    __shared__ int carry_s;
    const int tid = threadIdx.x;
    const int lane = tid & 63;
    const int wv = tid >> 6;
    if (tid == 0) carry_s = 0;
    __syncthreads();
    for (int base = 0; base < SCAN_V4; base += 1024) {
        int i4 = base + tid;
        int4 v = (i4 < SCAN_V4) ? ((const int4*)counts)[i4] : make_int4(0, 0, 0, 0);
        int s1 = v.x, s2 = s1 + v.y, s3 = s2 + v.z, s4 = s3 + v.w;
        int sc = s4;
#pragma unroll
        for (int off = 1; off < 64; off <<= 1) {
            int t = __shfl_up(sc, off, 64);
            if (lane >= off) sc += t;
        }
        if (lane == 63) wsum[wv] = sc;
        __syncthreads();
        int wprefix = 0;
#pragma unroll
        for (int w = 0; w < 16; ++w) {
            int t = wsum[w];
            if (w < wv) wprefix += t;
        }
        int excl = carry_s + wprefix + (sc - s4);
        if (i4 < SCAN_V4) {
            int4 o = make_int4(excl, excl + s1, excl + s2, excl + s3);
            ((int4*)row_start)[i4] = o;
            ((int4*)cursor)[i4] = o;
        }
        __syncthreads();
        if (tid == 0) {
            int tot = 0;
#pragma unroll
            for (int w = 0; w < 16; ++w) tot += wsum[w];
            carry_s += tot;
        }
        __syncthreads();
    }
    if (tid == 0) row_start[N_NODES] = carry_s;
}

// ---------------- K2b: edge attention + CSR scatter (int4, 4 edges/thread) ---
__global__ __launch_bounds__(256) void k2b_scatter(const int* __restrict__ ei,
                                                   const float* __restrict__ s,
                                                   const float* __restrict__ d,
                                                   int* __restrict__ cursor,
                                                   uint2* __restrict__ sorted) {
    int i = blockIdx.x * 256 + threadIdx.x;   // grid 1563, guard
    if (i >= N_EDGES / 4) return;
    int4 sv = ((const int4*)ei)[i];
    int4 dv = ((const int4*)(ei + N_EDGES))[i];
    float s0 = s[sv.x], s1 = s[sv.y], s2 = s[sv.z], s3 = s[sv.w];
    float dd0 = d[dv.x], dd1 = d[dv.y], dd2 = d[dv.z], dd3 = d[dv.w];
    float e0 = s0 + dd0; e0 = (e0 > 0.f) ? e0 : 0.2f * e0;
    float e1 = s1 + dd1; e1 = (e1 > 0.f) ? e1 : 0.2f * e1;
    float e2 = s2 + dd2; e2 = (e2 > 0.f) ? e2 : 0.2f * e2;
    float e3 = s3 + dd3; e3 = (e3 > 0.f) ? e3 : 0.2f * e3;
    float x0 = __expf(e0), x1 = __expf(e1), x2 = __expf(e2), x3 = __expf(e3);
    int p0 = atomicAdd(&cursor[dv.x], 1);
    int p1 = atomicAdd(&cursor[dv.y], 1);
    int p2 = atomicAdd(&cursor[dv.z], 1);
    int p3 = atomicAdd(&cursor[dv.w], 1);
    sorted[p0] = make_uint2((unsigned)sv.x, __float_as_uint(x0));
    sorted[p1] = make_uint2((unsigned)sv.y, __float_as_uint(x1));
    sorted[p2] = make_uint2((unsigned)sv.z, __float_as_uint(x2));
    sorted[p3] = make_uint2((unsigned)sv.w, __float_as_uint(x3));
}

// ---------------- K3: aggregation only (bf16 gather, 8-lane edge groups) -----
// one wave/node; 8 edges/wave in parallel x unroll 2 = 16 gathers in flight.
// lane owns 8 channels via one uint4 (bf16x8). No LDS, no epilogue.
__global__ __launch_bounds__(256) void k3_agg(const uint2* __restrict__ sorted,
                                              const int* __restrict__ row_start,
                                              const uint4* __restrict__ h4,
                                              uint4* __restrict__ zp) {
    const int lane = threadIdx.x & 63;
    const int node = blockIdx.x * 4 + (threadIdx.x >> 6);  // grid 25000 exact
    const int l8 = lane & 7;
    const int grp = lane >> 3;
    const int beg = row_start[node];
    const int end = row_start[node + 1];
    float a0 = 0.f, a1 = 0.f, a2 = 0.f, a3 = 0.f;
    float a4 = 0.f, a5 = 0.f, a6 = 0.f, a7 = 0.f, se = 0.f;
    int j = beg + grp;
    for (; j + 8 < end; j += 16) {
        uint2 r0 = sorted[j];
        uint2 r1 = sorted[j + 8];
        uint4 g0 = h4[r0.x * 8u + l8];
        uint4 g1 = h4[r1.x * 8u + l8];
        float e0 = __uint_as_float(r0.y), e1 = __uint_as_float(r1.y);
        se += e0 + e1;
        a0 += e0 * blo(g0.x) + e1 * blo(g1.x);
        a1 += e0 * bhi(g0.x) + e1 * bhi(g1.x);
        a2 += e0 * blo(g0.y) + e1 * blo(g1.y);
        a3 += e0 * bhi(g0.y) + e1 * bhi(g1.y);
        a4 += e0 * blo(g0.z) + e1 * blo(g1.z);
        a5 += e0 * bhi(g0.z) + e1 * bhi(g1.z);
        a6 += e0 * blo(g0.w) + e1 * blo(g1.w);
        a7 += e0 * bhi(g0.w) + e1 * bhi(g1.w);
    }
    if (j < end) {   // at most one tail edge per group
        uint2 r = sorted[j];
        uint4 g = h4[r.x * 8u + l8];
        float e = __uint_as_float(r.y);
        se += e;
        a0 += e * blo(g.x); a1 += e * bhi(g.x);
        a2 += e * blo(g.y); a3 += e * bhi(g.y);
        a4 += e * blo(g.z); a5 += e * bhi(g.z);
        a6 += e * blo(g.w); a7 += e * bhi(g.w);
    }
#pragma unroll
    for (int off = 8; off <= 32; off <<= 1) {
        a0 += __shfl_xor(a0, off, 64); a1 += __shfl_xor(a1, off, 64);
        a2 += __shfl_xor(a2, off, 64); a3 += __shfl_xor(a3, off, 64);
        a4 += __shfl_xor(a4, off, 64); a5 += __shfl_xor(a5, off, 64);
        a6 += __shfl_xor(a6, off, 64); a7 += __shfl_xor(a7, off, 64);
        se += __shfl_xor(se, off, 64);
    }
    if (grp == 0) {
        float inv = 1.f / (se + 1e-9f);
        uint4 o;
        o.x = bf16r(fmaxf(a0 * inv, 0.f)) | (bf16r(fmaxf(a1 * inv, 0.f)) << 16);
        o.y = bf16r(fmaxf(a2 * inv, 0.f)) | (bf16r(fmaxf(a3 * inv, 0.f)) << 16);
        o.z = bf16r(fmaxf(a4 * inv, 0.f)) | (bf16r(fmaxf(a5 * inv, 0.f)) << 16);
        o.w = bf16r(fmaxf(a6 * inv, 0.f)) | (bf16r(fmaxf(a7 * inv, 0.f)) << 16);
        zp[node * 8 + l8] = o;   // relu'd, normalized, bf16x8
    }
}

// ---------------- K4: out = z @ W_out^T + b_out (reg-tiled GEMM) -------------
// 128 nodes x 64 outs per block; thread = 4 rows x 8 cols; K=64.
#define K4_M 128
#define ZPAD 133
#define WPAD4 68

__global__ __launch_bounds__(256) void k4_out(const uint2* __restrict__ zp2,
                                              const float* __restrict__ W_out,
                                              const float* __restrict__ b_out,
                                              float* __restrict__ out) {
    __shared__ float zsT[HID * ZPAD];     // [k][m], 34,048 B
    __shared__ float wsT[HID * WPAD4];    // [k][c], 17,408 B
    const int tid = threadIdx.x;
    const int m0g = blockIdx.x * K4_M;    // grid 782, last block partial
    for (int i = tid; i < OUT_DIM * HID; i += 256) {
        int c = i >> 6, k = i & 63;
        wsT[k * WPAD4 + c] = W_out[i];
    }
    for (int i = tid; i < K4_M * 16; i += 256) {   // unpack bf16 z -> fp32 zsT
        int m = i >> 4, q = i & 15;
        int row = m0g + m;
        uint2 v = (row < N_NODES) ? zp2[row * 16 + q] : make_uint2(0u, 0u);
        int kb = q * 4;
        zsT[(kb + 0) * ZPAD + m] = blo(v.x);
        zsT[(kb + 1) * ZPAD + m] = bhi(v.x);
        zsT[(kb + 2) * ZPAD + m] = blo(v.y);
        zsT[(kb + 3) * ZPAD + m] = bhi(v.y);
    }
    __syncthreads();
    const int m0 = (tid & 31) * 4;
    const int c0 = (tid >> 5) * 8;
    float acc[4][8] = {};
#pragma unroll 4
    for (int k = 0; k < HID; ++k) {
        const float4 zv = *(const float4*)&zsT[k * ZPAD + m0];
        const float4 wa = *(const float4*)&wsT[k * WPAD4 + c0];
        const float4 wb = *(const float4*)&wsT[k * WPAD4 + c0 + 4];
#pragma unroll
        for (int i2 = 0; i2 < 4; ++i2) {
            float zi = (&zv.x)[i2];
            acc[i2][0] += zi * wa.x; acc[i2][1] += zi * wa.y;
            acc[i2][2] += zi * wa.z; acc[i2][3] += zi * wa.w;
            acc[i2][4] += zi * wb.x; acc[i2][5] += zi * wb.y;
            acc[i2][6] += zi * wb.z; acc[i2][7] += zi * wb.w;
        }
    }
    const float4 b0 = *(const float4*)&b_out[c0];
    const float4 b1 = *(const float4*)&b_out[c0 + 4];
#pragma unroll
    for (int i2 = 0; i2 < 4; ++i2) {
        int row = m0g + m0 + i2;
        if (row < N_NODES) {
            *(float4*)&out[row * OUT_DIM + c0] =
                make_float4(acc[i2][0] + b0.x, acc[i2][1] + b0.y,
                            acc[i2][2] + b0.z, acc[i2][3] + b0.w);
            *(float4*)&out[row * OUT_DIM + c0 + 4] =
                make_float4(acc[i2][4] + b1.x, acc[i2][5] + b1.y,
                            acc[i2][6] + b1.z, acc[i2][7] + b1.w);
        }
    }
}

extern "C" void kernel_launch(void* const* d_in, const int* in_sizes, int n_in,
                              void* d_out, int out_size, void* d_ws, size_t ws_size,
                              hipStream_t stream) {
    const float* x     = (const float*)d_in[0];
    const int*   ei    = (const int*)d_in[1];
    const float* W_lin = (const float*)d_in[2];
    const float* att   = (const float*)d_in[3];
    const float* W_out = (const float*)d_in[4];
    const float* b_out = (const float*)d_in[5];
    float* out = (float*)d_out;

    // workspace layout (~40.4 MB, all 16B-aligned)
    char* ws = (char*)d_ws;
    unsigned* h2        = (unsigned*)(ws);                    // 12,800,000 B (bf16 h)
    float*    s         = (float*)(ws + 12800000);            //    400,000 B
    float*    d         = (float*)(ws + 13200000);            //    400,000 B
    int*      counts    = (int*)  (ws + 13600000);            //    400,000 B
    int*      row_start = (int*)  (ws + 14000000);            //    400,016 B
    int*      cursor    = (int*)  (ws + 14400016);            //    400,000 B
    uint2*    sorted    = (uint2*)(ws + 14800016);            // 12,800,000 B
    unsigned* zp        = (unsigned*)(ws + 27600016);         // 12,800,000 B (bf16 z)

    hipMemsetAsync(counts, 0, N_NODES * sizeof(int), stream);

    k1_linear<<<(N_NODES + K1_ROWS - 1) / K1_ROWS, 256, 0, stream>>>(
        x, W_lin, att, (uint2*)h2, s, d);
    k2a_count<<<(N_EDGES / 4 + 255) / 256, 256, 0, stream>>>(ei, counts);
    k_scan<<<1, 1024, 0, stream>>>(counts, row_start, cursor);
    k2b_scatter<<<(N_EDGES / 4 + 255) / 256, 256, 0, stream>>>(ei, s, d, cursor, sorted);
    k3_agg<<<N_NODES / 4, 256, 0, stream>>>(sorted, row_start, (const uint4*)h2, (uint4*)zp);
    k4_out<<<(N_NODES + K4_M - 1) / K4_M, 256, 0, stream>>>(
        (const uint2*)zp, W_out, b_out, out);
}

// Round 5
// 379.331 us; speedup vs baseline: 1.2988x; 1.2988x over previous
//
#include <hip/hip_runtime.h>

#define N_NODES 100000
#define N_EDGES 1600000
#define IN_DIM 128
#define HID 64
#define OUT_DIM 64

__device__ __forceinline__ unsigned bf16r(float f) {   // fp32 -> bf16 bits, RNE
    unsigned u = __float_as_uint(f);
    return (u + 0x7FFFu + ((u >> 16) & 1u)) >> 16;
}
__device__ __forceinline__ float blo(unsigned u) { return __uint_as_float(u << 16); }
__device__ __forceinline__ float bhi(unsigned u) { return __uint_as_float(u & 0xFFFF0000u); }

// ---------------- K1: h2(bf16) = x @ W_lin^T ; s = h@att[:64]; d = h@att[64:] ----
#define K1_ROWS 64
#define K1PAD 68

__global__ __launch_bounds__(256) void k1_linear(const float* __restrict__ x,
                                                 const float* __restrict__ W,
                                                 const float* __restrict__ att,
                                                 uint2* __restrict__ h2v,
                                                 float* __restrict__ s,
                                                 float* __restrict__ d) {
    __shared__ float xsT[IN_DIM * K1PAD];   // 34,816 B
    __shared__ float wsT[IN_DIM * K1PAD];   // 34,816 B
    __shared__ float satt[2 * HID];
    __shared__ float sacc[K1_ROWS], dacc[K1_ROWS];
    const int tid = threadIdx.x;
    const int row0 = blockIdx.x * K1_ROWS;  // grid 1563, last block partial

    if (tid < 128) satt[tid] = att[tid];
    if (tid < K1_ROWS) { sacc[tid] = 0.f; dacc[tid] = 0.f; }
    for (int i = tid; i < HID * IN_DIM; i += 256) {
        int c = i >> 7, k = i & 127;
        wsT[k * K1PAD + c] = W[i];
    }
    for (int i = tid; i < K1_ROWS * IN_DIM; i += 256) {
        int r = i >> 7, k = i & 127;
        int row = row0 + r;
        xsT[k * K1PAD + r] = (row < N_NODES) ? x[row * IN_DIM + k] : 0.f;
    }
    __syncthreads();

    const int r0 = (tid & 15) * 4;
    const int c0 = (tid >> 4) * 4;
    float acc[4][4] = {};
#pragma unroll 4
    for (int k = 0; k < IN_DIM; ++k) {
        const float4 xv = *(const float4*)&xsT[k * K1PAD + r0];
        const float4 wv = *(const float4*)&wsT[k * K1PAD + c0];
#pragma unroll
        for (int i2 = 0; i2 < 4; ++i2) {
            float xi = (&xv.x)[i2];
            acc[i2][0] += xi * wv.x; acc[i2][1] += xi * wv.y;
            acc[i2][2] += xi * wv.z; acc[i2][3] += xi * wv.w;
        }
    }
#pragma unroll
    for (int i2 = 0; i2 < 4; ++i2) {
        int row = row0 + r0 + i2;
        unsigned p0 = bf16r(acc[i2][0]) | (bf16r(acc[i2][1]) << 16);
        unsigned p1 = bf16r(acc[i2][2]) | (bf16r(acc[i2][3]) << 16);
        if (row < N_NODES) h2v[row * 16 + (c0 >> 2)] = make_uint2(p0, p1);
        float ps = 0.f, pd = 0.f;
#pragma unroll
        for (int j = 0; j < 4; ++j) {
            ps += acc[i2][j] * satt[c0 + j];
            pd += acc[i2][j] * satt[HID + c0 + j];
        }
        atomicAdd(&sacc[r0 + i2], ps);
        atomicAdd(&dacc[r0 + i2], pd);
    }
    __syncthreads();
    if (tid < K1_ROWS) {
        int row = row0 + tid;
        if (row < N_NODES) { s[row] = sacc[tid]; d[row] = dacc[tid]; }
    }
}

// ---------------- K2a: histogram + per-edge rank (atomic returns rank) -------
__global__ __launch_bounds__(256) void k2a_rank(const int* __restrict__ ei,
                                                int* __restrict__ counts,
                                                int* __restrict__ rank) {
    int i = blockIdx.x * 256 + threadIdx.x;  // grid 6250 exact
    int dstv = ei[N_EDGES + i];
    rank[i] = atomicAdd(&counts[dstv], 1);
}

// ---------------- scan: exclusive prefix over counts (int4-vectorized) -------
#define SCAN_V4 (N_NODES / 4)   // 25000, exact
__global__ __launch_bounds__(1024) void k_scan(const int* __restrict__ counts,
                                               int* __restrict__ row_start) {
    __shared__ int wsum[16];
    __shared__ int carry_s;
    const int tid = threadIdx.x;
    const int lane = tid & 63;
    const int wv = tid >> 6;
    if (tid == 0) carry_s = 0;
    __syncthreads();
    for (int base = 0; base < SCAN_V4; base += 1024) {
        int i4 = base + tid;
        int4 v = (i4 < SCAN_V4) ? ((const int4*)counts)[i4] : make_int4(0, 0, 0, 0);
        int s1 = v.x, s2 = s1 + v.y, s3 = s2 + v.z, s4 = s3 + v.w;
        int sc = s4;
#pragma unroll
        for (int off = 1; off < 64; off <<= 1) {
            int t = __shfl_up(sc, off, 64);
            if (lane >= off) sc += t;
        }
        if (lane == 63) wsum[wv] = sc;
        __syncthreads();
        int wprefix = 0;
#pragma unroll
        for (int w = 0; w < 16; ++w) {
            int t = wsum[w];
            if (w < wv) wprefix += t;
        }
        int excl = carry_s + wprefix + (sc - s4);
        if (i4 < SCAN_V4) {
            ((int4*)row_start)[i4] = make_int4(excl, excl + s1, excl + s2, excl + s3);
        }
        __syncthreads();
        if (tid == 0) {
            int tot = 0;
#pragma unroll
            for (int w = 0; w < 16; ++w) tot += wsum[w];
            carry_s += tot;
        }
        __syncthreads();
    }
    if (tid == 0) row_start[N_NODES] = carry_s;
}

// ---------------- K2b: edge attention + atomic-free CSR scatter --------------
__global__ __launch_bounds__(256) void k2b_scatter(const int* __restrict__ ei,
                                                   const float* __restrict__ s,
                                                   const float* __restrict__ d,
                                                   const int* __restrict__ row_start,
                                                   const int* __restrict__ rank,
                                                   uint2* __restrict__ sorted) {
    int i = blockIdx.x * 256 + threadIdx.x;  // grid 6250 exact
    int srcv = ei[i];
    int dstv = ei[N_EDGES + i];
    float e = s[srcv] + d[dstv];
    e = (e > 0.f) ? e : 0.2f * e;            // leaky_relu(0.2)
    float ex = __expf(e);                    // shift-invariant: no global max needed
    int pos = row_start[dstv] + rank[i];
    sorted[pos] = make_uint2((unsigned)srcv, __float_as_uint(ex));
}

// ---------------- K3: aggregation only (bf16 gather, 8-lane edge groups) -----
__global__ __launch_bounds__(256) void k3_agg(const uint2* __restrict__ sorted,
                                              const int* __restrict__ row_start,
                                              const uint4* __restrict__ h4,
                                              uint4* __restrict__ zp) {
    const int lane = threadIdx.x & 63;
    const int node = blockIdx.x * 4 + (threadIdx.x >> 6);  // grid 25000 exact
    const int l8 = lane & 7;
    const int grp = lane >> 3;
    const int beg = row_start[node];
    const int end = row_start[node + 1];
    float a0 = 0.f, a1 = 0.f, a2 = 0.f, a3 = 0.f;
    float a4 = 0.f, a5 = 0.f, a6 = 0.f, a7 = 0.f, se = 0.f;
    int j = beg + grp;
    for (; j + 8 < end; j += 16) {
        uint2 r0 = sorted[j];
        uint2 r1 = sorted[j + 8];
        uint4 g0 = h4[r0.x * 8u + l8];
        uint4 g1 = h4[r1.x * 8u + l8];
        float e0 = __uint_as_float(r0.y), e1 = __uint_as_float(r1.y);
        se += e0 + e1;
        a0 += e0 * blo(g0.x) + e1 * blo(g1.x);
        a1 += e0 * bhi(g0.x) + e1 * bhi(g1.x);
        a2 += e0 * blo(g0.y) + e1 * blo(g1.y);
        a3 += e0 * bhi(g0.y) + e1 * bhi(g1.y);
        a4 += e0 * blo(g0.z) + e1 * blo(g1.z);
        a5 += e0 * bhi(g0.z) + e1 * bhi(g1.z);
        a6 += e0 * blo(g0.w) + e1 * blo(g1.w);
        a7 += e0 * bhi(g0.w) + e1 * bhi(g1.w);
    }
    if (j < end) {   // at most one tail edge per group
        uint2 r = sorted[j];
        uint4 g = h4[r.x * 8u + l8];
        float e = __uint_as_float(r.y);
        se += e;
        a0 += e * blo(g.x); a1 += e * bhi(g.x);
        a2 += e * blo(g.y); a3 += e * bhi(g.y);
        a4 += e * blo(g.z); a5 += e * bhi(g.z);
        a6 += e * blo(g.w); a7 += e * bhi(g.w);
    }
#pragma unroll
    for (int off = 8; off <= 32; off <<= 1) {
        a0 += __shfl_xor(a0, off, 64); a1 += __shfl_xor(a1, off, 64);
        a2 += __shfl_xor(a2, off, 64); a3 += __shfl_xor(a3, off, 64);
        a4 += __shfl_xor(a4, off, 64); a5 += __shfl_xor(a5, off, 64);
        a6 += __shfl_xor(a6, off, 64); a7 += __shfl_xor(a7, off, 64);
        se += __shfl_xor(se, off, 64);
    }
    if (grp == 0) {
        float inv = 1.f / (se + 1e-9f);
        uint4 o;
        o.x = bf16r(fmaxf(a0 * inv, 0.f)) | (bf16r(fmaxf(a1 * inv, 0.f)) << 16);
        o.y = bf16r(fmaxf(a2 * inv, 0.f)) | (bf16r(fmaxf(a3 * inv, 0.f)) << 16);
        o.z = bf16r(fmaxf(a4 * inv, 0.f)) | (bf16r(fmaxf(a5 * inv, 0.f)) << 16);
        o.w = bf16r(fmaxf(a6 * inv, 0.f)) | (bf16r(fmaxf(a7 * inv, 0.f)) << 16);
        zp[node * 8 + l8] = o;   // relu'd, normalized, bf16x8
    }
}

// ---------------- K4: out = z @ W_out^T + b_out (reg-tiled GEMM) -------------
#define K4_M 128
#define ZPAD 133
#define WPAD4 68

__global__ __launch_bounds__(256) void k4_out(const uint2* __restrict__ zp2,
                                              const float* __restrict__ W_out,
                                              const float* __restrict__ b_out,
                                              float* __restrict__ out) {
    __shared__ float zsT[HID * ZPAD];     // [k][m], 34,048 B
    __shared__ float wsT[HID * WPAD4];    // [k][c], 17,408 B
    const int tid = threadIdx.x;
    const int m0g = blockIdx.x * K4_M;    // grid 782, last block partial
    for (int i = tid; i < OUT_DIM * HID; i += 256) {
        int c = i >> 6, k = i & 63;
        wsT[k * WPAD4 + c] = W_out[i];
    }
    for (int i = tid; i < K4_M * 16; i += 256) {   // unpack bf16 z -> fp32 zsT
        int m = i >> 4, q = i & 15;
        int row = m0g + m;
        uint2 v = (row < N_NODES) ? zp2[row * 16 + q] : make_uint2(0u, 0u);
        int kb = q * 4;
        zsT[(kb + 0) * ZPAD + m] = blo(v.x);
        zsT[(kb + 1) * ZPAD + m] = bhi(v.x);
        zsT[(kb + 2) * ZPAD + m] = blo(v.y);
        zsT[(kb + 3) * ZPAD + m] = bhi(v.y);
    }
    __syncthreads();
    const int m0 = (tid & 31) * 4;
    const int c0 = (tid >> 5) * 8;
    float acc[4][8] = {};
#pragma unroll 4
    for (int k = 0; k < HID; ++k) {
        const float4 zv = *(const float4*)&zsT[k * ZPAD + m0];
        const float4 wa = *(const float4*)&wsT[k * WPAD4 + c0];
        const float4 wb = *(const float4*)&wsT[k * WPAD4 + c0 + 4];
#pragma unroll
        for (int i2 = 0; i2 < 4; ++i2) {
            float zi = (&zv.x)[i2];
            acc[i2][0] += zi * wa.x; acc[i2][1] += zi * wa.y;
            acc[i2][2] += zi * wa.z; acc[i2][3] += zi * wa.w;
            acc[i2][4] += zi * wb.x; acc[i2][5] += zi * wb.y;
            acc[i2][6] += zi * wb.z; acc[i2][7] += zi * wb.w;
        }
    }
    const float4 b0 = *(const float4*)&b_out[c0];
    const float4 b1 = *(const float4*)&b_out[c0 + 4];
#pragma unroll
    for (int i2 = 0; i2 < 4; ++i2) {
        int row = m0g + m0 + i2;
        if (row < N_NODES) {
            *(float4*)&out[row * OUT_DIM + c0] =
                make_float4(acc[i2][0] + b0.x, acc[i2][1] + b0.y,
                            acc[i2][2] + b0.z, acc[i2][3] + b0.w);
            *(float4*)&out[row * OUT_DIM + c0 + 4] =
                make_float4(acc[i2][4] + b1.x, acc[i2][5] + b1.y,
                            acc[i2][6] + b1.z, acc[i2][7] + b1.w);
        }
    }
}

extern "C" void kernel_launch(void* const* d_in, const int* in_sizes, int n_in,
                              void* d_out, int out_size, void* d_ws, size_t ws_size,
                              hipStream_t stream) {
    const float* x     = (const float*)d_in[0];
    const int*   ei    = (const int*)d_in[1];
    const float* W_lin = (const float*)d_in[2];
    const float* att   = (const float*)d_in[3];
    const float* W_out = (const float*)d_in[4];
    const float* b_out = (const float*)d_in[5];
    float* out = (float*)d_out;

    // workspace layout (~40.4 MB). NOTE: rank aliases zp (disjoint lifetimes:
    // rank lives [k2a, k2b]; zp lives [k3, k4]).
    char* ws = (char*)d_ws;
    unsigned* h2        = (unsigned*)(ws);                    // 12,800,000 B (bf16 h)
    float*    s         = (float*)(ws + 12800000);            //    400,000 B
    float*    d         = (float*)(ws + 13200000);            //    400,000 B
    int*      counts    = (int*)  (ws + 13600000);            //    400,000 B
    int*      row_start = (int*)  (ws + 14000000);            //    400,016 B
    uint2*    sorted    = (uint2*)(ws + 14800016);            // 12,800,000 B
    unsigned* zp        = (unsigned*)(ws + 27600016);         // 12,800,000 B (bf16 z)
    int*      rank      = (int*)zp;                           //  6,400,000 B (alias)

    hipMemsetAsync(counts, 0, N_NODES * sizeof(int), stream);

    k1_linear<<<(N_NODES + K1_ROWS - 1) / K1_ROWS, 256, 0, stream>>>(
        x, W_lin, att, (uint2*)h2, s, d);
    k2a_rank<<<N_EDGES / 256, 256, 0, stream>>>(ei, counts, rank);
    k_scan<<<1, 1024, 0, stream>>>(counts, row_start);
    k2b_scatter<<<N_EDGES / 256, 256, 0, stream>>>(ei, s, d, row_start, rank, sorted);
    k3_agg<<<N_NODES / 4, 256, 0, stream>>>(sorted, row_start, (const uint4*)h2, (uint4*)zp);
    k4_out<<<(N_NODES + K4_M - 1) / K4_M, 256, 0, stream>>>(
        (const uint2*)zp, W_out, b_out, out);
}

// Round 6
// 330.621 us; speedup vs baseline: 1.4901x; 1.1473x over previous
//
#include <hip/hip_runtime.h>

#define N_NODES 100000
#define N_EDGES 1600000
#define IN_DIM 128
#define HID 64
#define OUT_DIM 64

typedef __attribute__((ext_vector_type(8))) short short8;
typedef __attribute__((ext_vector_type(4))) float f32x4;
union FragU { short8 v; unsigned u[4]; };

__device__ __forceinline__ unsigned bf16r(float f) {   // fp32 -> bf16 bits, RNE
    unsigned u = __float_as_uint(f);
    return (u + 0x7FFFu + ((u >> 16) & 1u)) >> 16;
}
__device__ __forceinline__ float blo(unsigned u) { return __uint_as_float(u << 16); }
__device__ __forceinline__ float bhi(unsigned u) { return __uint_as_float(u & 0xFFFF0000u); }

// ---------------- K1: h(bf16) = x @ W_lin^T via MFMA; s,d exact fp32 ---------
// s = h@att[:64] == x@(W^T att[:64]) = x@w_s  -> computed from fp32 x directly.
// One wave per 16-row tile; W (as 16 bf16 B-frags) register-resident per wave.
// 6250 tiles exact (100000 = 6250*16); grid 1563 blocks x 4 waves (2 idle).
__global__ __launch_bounds__(256) void k1_mfma(const float* __restrict__ x,
                                               const float* __restrict__ W,
                                               const float* __restrict__ att,
                                               uint4* __restrict__ h4,
                                               float* __restrict__ s,
                                               float* __restrict__ d) {
    __shared__ float wsL[IN_DIM], wdL[IN_DIM];
    __shared__ float scratch[4 * 64 * 17];   // per-wave [col][row] stride 17 (17,408 B)
    const int tid = threadIdx.x;

    // w_s[k] = sum_c W[c][k]*att[c]; coalesced over tid for each c
    if (tid < IN_DIM) {
        float as = 0.f, ad = 0.f;
        for (int c = 0; c < HID; ++c) {
            float w = W[c * IN_DIM + tid];
            as += w * att[c];
            ad += w * att[HID + c];
        }
        wsL[tid] = as; wdL[tid] = ad;
    }
    __syncthreads();

    const int lane = tid & 63;
    const int wv = tid >> 6;
    const int l16 = lane & 15;
    const int quad = lane >> 4;
    const int tile = blockIdx.x * 4 + wv;

    // B-frags: bfrag[t][ks] holds W^T[k][col] for col = t*16+l16, k = ks*32+quad*8+j
    FragU bfrag[4][4];
#pragma unroll
    for (int t = 0; t < 4; ++t) {
#pragma unroll
        for (int ks = 0; ks < 4; ++ks) {
            const float* wp = &W[(t * 16 + l16) * IN_DIM + ks * 32 + quad * 8];
            float4 wa = *(const float4*)wp;
            float4 wb = *(const float4*)(wp + 4);
            bfrag[t][ks].u[0] = bf16r(wa.x) | (bf16r(wa.y) << 16);
            bfrag[t][ks].u[1] = bf16r(wa.z) | (bf16r(wa.w) << 16);
            bfrag[t][ks].u[2] = bf16r(wb.x) | (bf16r(wb.y) << 16);
            bfrag[t][ks].u[3] = bf16r(wb.z) | (bf16r(wb.w) << 16);
        }
    }

    if (tile < N_NODES / 16) {
        const int rowbase = tile * 16;
        const float* xrow = &x[(size_t)(rowbase + l16) * IN_DIM];
        f32x4 acc[4] = {{0.f,0.f,0.f,0.f},{0.f,0.f,0.f,0.f},
                        {0.f,0.f,0.f,0.f},{0.f,0.f,0.f,0.f}};
        float ps = 0.f, pd = 0.f;
#pragma unroll
        for (int ks = 0; ks < 4; ++ks) {
            const int k0 = ks * 32 + quad * 8;
            float4 xa = *(const float4*)&xrow[k0];
            float4 xb = *(const float4*)&xrow[k0 + 4];
            ps += xa.x * wsL[k0]     + xa.y * wsL[k0 + 1]
                + xa.z * wsL[k0 + 2] + xa.w * wsL[k0 + 3]
                + xb.x * wsL[k0 + 4] + xb.y * wsL[k0 + 5]
                + xb.z * wsL[k0 + 6] + xb.w * wsL[k0 + 7];
            pd += xa.x * wdL[k0]     + xa.y * wdL[k0 + 1]
                + xa.z * wdL[k0 + 2] + xa.w * wdL[k0 + 3]
                + xb.x * wdL[k0 + 4] + xb.y * wdL[k0 + 5]
                + xb.z * wdL[k0 + 6] + xb.w * wdL[k0 + 7];
            FragU af;
            af.u[0] = bf16r(xa.x) | (bf16r(xa.y) << 16);
            af.u[1] = bf16r(xa.z) | (bf16r(xa.w) << 16);
            af.u[2] = bf16r(xb.x) | (bf16r(xb.y) << 16);
            af.u[3] = bf16r(xb.z) | (bf16r(xb.w) << 16);
#pragma unroll
            for (int t = 0; t < 4; ++t)
                acc[t] = __builtin_amdgcn_mfma_f32_16x16x32_bf16(
                    af.v, bfrag[t][ks].v, acc[t], 0, 0, 0);
        }
        // s,d: reduce the 4 k-chunk partials of row l16 (lanes l16, +16, +32, +48)
        ps += __shfl_xor(ps, 16, 64); ps += __shfl_xor(ps, 32, 64);
        pd += __shfl_xor(pd, 16, 64); pd += __shfl_xor(pd, 32, 64);
        if (quad == 0) { s[rowbase + l16] = ps; d[rowbase + l16] = pd; }
        // epilogue: per-wave LDS transpose [col][row], then coalesced uint4 store
        float* sc = &scratch[wv * 64 * 17];
#pragma unroll
        for (int t = 0; t < 4; ++t)
#pragma unroll
            for (int r = 0; r < 4; ++r)
                sc[(l16 + 16 * t) * 17 + quad * 4 + r] = acc[t][r];
        // same-wave RAW: compiler inserts lgkmcnt wait; no barrier needed
#pragma unroll
        for (int i = 0; i < 2; ++i) {
            int idx = i * 64 + lane;
            int nrow = idx >> 3, q = idx & 7;
            float v0 = sc[(q * 8 + 0) * 17 + nrow];
            float v1 = sc[(q * 8 + 1) * 17 + nrow];
            float v2 = sc[(q * 8 + 2) * 17 + nrow];
            float v3 = sc[(q * 8 + 3) * 17 + nrow];
            float v4 = sc[(q * 8 + 4) * 17 + nrow];
            float v5 = sc[(q * 8 + 5) * 17 + nrow];
            float v6 = sc[(q * 8 + 6) * 17 + nrow];
            float v7 = sc[(q * 8 + 7) * 17 + nrow];
            uint4 o;
            o.x = bf16r(v0) | (bf16r(v1) << 16);
            o.y = bf16r(v2) | (bf16r(v3) << 16);
            o.z = bf16r(v4) | (bf16r(v5) << 16);
            o.w = bf16r(v6) | (bf16r(v7) << 16);
            h4[(size_t)(rowbase + nrow) * 8 + q] = o;
        }
    }
}

// ---------------- K2a: histogram + per-edge rank (atomic returns rank) -------
__global__ __launch_bounds__(256) void k2a_rank(const int* __restrict__ ei,
                                                int* __restrict__ counts,
                                                int* __restrict__ rank) {
    int i = blockIdx.x * 256 + threadIdx.x;  // grid 6250 exact
    int dstv = ei[N_EDGES + i];
    rank[i] = atomicAdd(&counts[dstv], 1);
}

// ---------------- scan: exclusive prefix over counts (int4-vectorized) -------
#define SCAN_V4 (N_NODES / 4)   // 25000, exact
__global__ __launch_bounds__(1024) void k_scan(const int* __restrict__ counts,
                                               int* __restrict__ row_start) {
    __shared__ int wsum[16];
    __shared__ int carry_s;
    const int tid = threadIdx.x;
    const int lane = tid & 63;
    const int wv = tid >> 6;
    if (tid == 0) carry_s = 0;
    __syncthreads();
    for (int base = 0; base < SCAN_V4; base += 1024) {
        int i4 = base + tid;
        int4 v = (i4 < SCAN_V4) ? ((const int4*)counts)[i4] : make_int4(0, 0, 0, 0);
        int s1 = v.x, s2 = s1 + v.y, s3 = s2 + v.z, s4 = s3 + v.w;
        int sc = s4;
#pragma unroll
        for (int off = 1; off < 64; off <<= 1) {
            int t = __shfl_up(sc, off, 64);
            if (lane >= off) sc += t;
        }
        if (lane == 63) wsum[wv] = sc;
        __syncthreads();
        int wprefix = 0;
#pragma unroll
        for (int w = 0; w < 16; ++w) {
            int t = wsum[w];
            if (w < wv) wprefix += t;
        }
        int excl = carry_s + wprefix + (sc - s4);
        if (i4 < SCAN_V4) {
            ((int4*)row_start)[i4] = make_int4(excl, excl + s1, excl + s2, excl + s3);
        }
        __syncthreads();
        if (tid == 0) {
            int tot = 0;
#pragma unroll
            for (int w = 0; w < 16; ++w) tot += wsum[w];
            carry_s += tot;
        }
        __syncthreads();
    }
    if (tid == 0) row_start[N_NODES] = carry_s;
}

// ---------------- K2b: edge attention + atomic-free CSR scatter --------------
__global__ __launch_bounds__(256) void k2b_scatter(const int* __restrict__ ei,
                                                   const float* __restrict__ s,
                                                   const float* __restrict__ d,
                                                   const int* __restrict__ row_start,
                                                   const int* __restrict__ rank,
                                                   uint2* __restrict__ sorted) {
    int i = blockIdx.x * 256 + threadIdx.x;  // grid 6250 exact
    int srcv = ei[i];
    int dstv = ei[N_EDGES + i];
    float e = s[srcv] + d[dstv];
    e = (e > 0.f) ? e : 0.2f * e;            // leaky_relu(0.2)
    float ex = __expf(e);                    // shift-invariant: no global max needed
    int pos = row_start[dstv] + rank[i];
    sorted[pos] = make_uint2((unsigned)srcv, __float_as_uint(ex));
}

// ---------------- K3: aggregation only (bf16 gather, 8-lane edge groups) -----
__global__ __launch_bounds__(256) void k3_agg(const uint2* __restrict__ sorted,
                                              const int* __restrict__ row_start,
                                              const uint4* __restrict__ h4,
                                              uint4* __restrict__ zp) {
    const int lane = threadIdx.x & 63;
    const int node = blockIdx.x * 4 + (threadIdx.x >> 6);  // grid 25000 exact
    const int l8 = lane & 7;
    const int grp = lane >> 3;
    const int beg = row_start[node];
    const int end = row_start[node + 1];
    float a0 = 0.f, a1 = 0.f, a2 = 0.f, a3 = 0.f;
    float a4 = 0.f, a5 = 0.f, a6 = 0.f, a7 = 0.f, se = 0.f;
    int j = beg + grp;
    for (; j + 8 < end; j += 16) {
        uint2 r0 = sorted[j];
        uint2 r1 = sorted[j + 8];
        uint4 g0 = h4[r0.x * 8u + l8];
        uint4 g1 = h4[r1.x * 8u + l8];
        float e0 = __uint_as_float(r0.y), e1 = __uint_as_float(r1.y);
        se += e0 + e1;
        a0 += e0 * blo(g0.x) + e1 * blo(g1.x);
        a1 += e0 * bhi(g0.x) + e1 * bhi(g1.x);
        a2 += e0 * blo(g0.y) + e1 * blo(g1.y);
        a3 += e0 * bhi(g0.y) + e1 * bhi(g1.y);
        a4 += e0 * blo(g0.z) + e1 * blo(g1.z);
        a5 += e0 * bhi(g0.z) + e1 * bhi(g1.z);
        a6 += e0 * blo(g0.w) + e1 * blo(g1.w);
        a7 += e0 * bhi(g0.w) + e1 * bhi(g1.w);
    }
    if (j < end) {   // at most one tail edge per group
        uint2 r = sorted[j];
        uint4 g = h4[r.x * 8u + l8];
        float e = __uint_as_float(r.y);
        se += e;
        a0 += e * blo(g.x); a1 += e * bhi(g.x);
        a2 += e * blo(g.y); a3 += e * bhi(g.y);
        a4 += e * blo(g.z); a5 += e * bhi(g.z);
        a6 += e * blo(g.w); a7 += e * bhi(g.w);
    }
#pragma unroll
    for (int off = 8; off <= 32; off <<= 1) {
        a0 += __shfl_xor(a0, off, 64); a1 += __shfl_xor(a1, off, 64);
        a2 += __shfl_xor(a2, off, 64); a3 += __shfl_xor(a3, off, 64);
        a4 += __shfl_xor(a4, off, 64); a5 += __shfl_xor(a5, off, 64);
        a6 += __shfl_xor(a6, off, 64); a7 += __shfl_xor(a7, off, 64);
        se += __shfl_xor(se, off, 64);
    }
    if (grp == 0) {
        float inv = 1.f / (se + 1e-9f);
        uint4 o;
        o.x = bf16r(fmaxf(a0 * inv, 0.f)) | (bf16r(fmaxf(a1 * inv, 0.f)) << 16);
        o.y = bf16r(fmaxf(a2 * inv, 0.f)) | (bf16r(fmaxf(a3 * inv, 0.f)) << 16);
        o.z = bf16r(fmaxf(a4 * inv, 0.f)) | (bf16r(fmaxf(a5 * inv, 0.f)) << 16);
        o.w = bf16r(fmaxf(a6 * inv, 0.f)) | (bf16r(fmaxf(a7 * inv, 0.f)) << 16);
        zp[node * 8 + l8] = o;   // relu'd, normalized, bf16x8
    }
}

// ---------------- K4: out = z @ W_out^T + b_out (reg-tiled GEMM) -------------
#define K4_M 128
#define ZPAD 133
#define WPAD4 68

__global__ __launch_bounds__(256) void k4_out(const uint2* __restrict__ zp2,
                                              const float* __restrict__ W_out,
                                              const float* __restrict__ b_out,
                                              float* __restrict__ out) {
    __shared__ float zsT[HID * ZPAD];     // [k][m], 34,048 B
    __shared__ float wsT[HID * WPAD4];    // [k][c], 17,408 B
    const int tid = threadIdx.x;
    const int m0g = blockIdx.x * K4_M;    // grid 782, last block partial
    for (int i = tid; i < OUT_DIM * HID; i += 256) {
        int c = i >> 6, k = i & 63;
        wsT[k * WPAD4 + c] = W_out[i];
    }
    for (int i = tid; i < K4_M * 16; i += 256) {   // unpack bf16 z -> fp32 zsT
        int m = i >> 4, q = i & 15;
        int row = m0g + m;
        uint2 v = (row < N_NODES) ? zp2[row * 16 + q] : make_uint2(0u, 0u);
        int kb = q * 4;
        zsT[(kb + 0) * ZPAD + m] = blo(v.x);
        zsT[(kb + 1) * ZPAD + m] = bhi(v.x);
        zsT[(kb + 2) * ZPAD + m] = blo(v.y);
        zsT[(kb + 3) * ZPAD + m] = bhi(v.y);
    }
    __syncthreads();
    const int m0 = (tid & 31) * 4;
    const int c0 = (tid >> 5) * 8;
    float acc[4][8] = {};
#pragma unroll 4
    for (int k = 0; k < HID; ++k) {
        const float4 zv = *(const float4*)&zsT[k * ZPAD + m0];
        const float4 wa = *(const float4*)&wsT[k * WPAD4 + c0];
        const float4 wb = *(const float4*)&wsT[k * WPAD4 + c0 + 4];
#pragma unroll
        for (int i2 = 0; i2 < 4; ++i2) {
            float zi = (&zv.x)[i2];
            acc[i2][0] += zi * wa.x; acc[i2][1] += zi * wa.y;
            acc[i2][2] += zi * wa.z; acc[i2][3] += zi * wa.w;
            acc[i2][4] += zi * wb.x; acc[i2][5] += zi * wb.y;
            acc[i2][6] += zi * wb.z; acc[i2][7] += zi * wb.w;
        }
    }
    const float4 b0 = *(const float4*)&b_out[c0];
    const float4 b1 = *(const float4*)&b_out[c0 + 4];
#pragma unroll
    for (int i2 = 0; i2 < 4; ++i2) {
        int row = m0g + m0 + i2;
        if (row < N_NODES) {
            *(float4*)&out[row * OUT_DIM + c0] =
                make_float4(acc[i2][0] + b0.x, acc[i2][1] + b0.y,
                            acc[i2][2] + b0.z, acc[i2][3] + b0.w);
            *(float4*)&out[row * OUT_DIM + c0 + 4] =
                make_float4(acc[i2][4] + b1.x, acc[i2][5] + b1.y,
                            acc[i2][6] + b1.z, acc[i2][7] + b1.w);
        }
    }
}

extern "C" void kernel_launch(void* const* d_in, const int* in_sizes, int n_in,
                              void* d_out, int out_size, void* d_ws, size_t ws_size,
                              hipStream_t stream) {
    const float* x     = (const float*)d_in[0];
    const int*   ei    = (const int*)d_in[1];
    const float* W_lin = (const float*)d_in[2];
    const float* att   = (const float*)d_in[3];
    const float* W_out = (const float*)d_in[4];
    const float* b_out = (const float*)d_in[5];
    float* out = (float*)d_out;

    // workspace layout (~40.4 MB). rank aliases zp (disjoint lifetimes).
    char* ws = (char*)d_ws;
    unsigned* h2        = (unsigned*)(ws);                    // 12,800,000 B (bf16 h)
    float*    s         = (float*)(ws + 12800000);            //    400,000 B
    float*    d         = (float*)(ws + 13200000);            //    400,000 B
    int*      counts    = (int*)  (ws + 13600000);            //    400,000 B
    int*      row_start = (int*)  (ws + 14000000);            //    400,016 B
    uint2*    sorted    = (uint2*)(ws + 14800016);            // 12,800,000 B
    unsigned* zp        = (unsigned*)(ws + 27600016);         // 12,800,000 B (bf16 z)
    int*      rank      = (int*)zp;                           //  6,400,000 B (alias)

    hipMemsetAsync(counts, 0, N_NODES * sizeof(int), stream);

    k1_mfma<<<(N_NODES / 16 + 3) / 4, 256, 0, stream>>>(
        x, W_lin, att, (uint4*)h2, s, d);
    k2a_rank<<<N_EDGES / 256, 256, 0, stream>>>(ei, counts, rank);
    k_scan<<<1, 1024, 0, stream>>>(counts, row_start);
    k2b_scatter<<<N_EDGES / 256, 256, 0, stream>>>(ei, s, d, row_start, rank, sorted);
    k3_agg<<<N_NODES / 4, 256, 0, stream>>>(sorted, row_start, (const uint4*)h2, (uint4*)zp);
    k4_out<<<(N_NODES + K4_M - 1) / K4_M, 256, 0, stream>>>(
        (const uint2*)zp, W_out, b_out, out);
}

// Round 7
// 322.557 us; speedup vs baseline: 1.5274x; 1.0250x over previous
//
#include <hip/hip_runtime.h>

#define N_NODES 100000
#define N_EDGES 1600000
#define IN_DIM 128
#define HID 64
#define OUT_DIM 64

typedef __attribute__((ext_vector_type(8))) short short8;
typedef __attribute__((ext_vector_type(4))) float f32x4;
union FragU { short8 v; unsigned u[4]; };

__device__ __forceinline__ unsigned bf16r(float f) {   // fp32 -> bf16 bits, RNE
    unsigned u = __float_as_uint(f);
    return (u + 0x7FFFu + ((u >> 16) & 1u)) >> 16;
}
__device__ __forceinline__ float blo(unsigned u) { return __uint_as_float(u << 16); }
__device__ __forceinline__ float bhi(unsigned u) { return __uint_as_float(u & 0xFFFF0000u); }

#define K1_BLOCKS 1563          // ceil(6250 tiles / 4 waves)
#define K2A_BLOCKS 1563         // ceil(400000 int4 / 256)

// ---------------- Fused K1 (MFMA linear) + K2A (histogram+rank) --------------
// Independent work co-scheduled: blocks [0,1563) do h/s/d; [1563,3126) do the
// edge histogram with 4 independent returning atomics per thread.
__global__ __launch_bounds__(256) void k1_k2a(const float* __restrict__ x,
                                              const float* __restrict__ W,
                                              const float* __restrict__ att,
                                              uint4* __restrict__ h4,
                                              float* __restrict__ s,
                                              float* __restrict__ d,
                                              const int* __restrict__ ei,
                                              int* __restrict__ counts,
                                              int* __restrict__ rank) {
    __shared__ float wsL[IN_DIM], wdL[IN_DIM];
    __shared__ float scratch[4 * 64 * 17];   // per-wave [col][row] stride 17
    const int tid = threadIdx.x;

    if (blockIdx.x >= K1_BLOCKS) {
        // ---- K2A: 4 edges/thread, 4 atomics in flight ----
        int i4 = (blockIdx.x - K1_BLOCKS) * 256 + tid;
        if (i4 < N_EDGES / 4) {
            int4 dv = ((const int4*)(ei + N_EDGES))[i4];
            int r0 = atomicAdd(&counts[dv.x], 1);
            int r1 = atomicAdd(&counts[dv.y], 1);
            int r2 = atomicAdd(&counts[dv.z], 1);
            int r3 = atomicAdd(&counts[dv.w], 1);
            ((int4*)rank)[i4] = make_int4(r0, r1, r2, r3);
        }
        return;
    }

    // ---- K1: h(bf16) = x @ W^T via MFMA; s,d exact fp32 from x@(W^T att) ----
    if (tid < IN_DIM) {
        float as = 0.f, ad = 0.f;
        for (int c = 0; c < HID; ++c) {
            float w = W[c * IN_DIM + tid];
            as += w * att[c];
            ad += w * att[HID + c];
        }
        wsL[tid] = as; wdL[tid] = ad;
    }
    __syncthreads();

    const int lane = tid & 63;
    const int wv = tid >> 6;
    const int l16 = lane & 15;
    const int quad = lane >> 4;
    const int tile = blockIdx.x * 4 + wv;

    FragU bfrag[4][4];
#pragma unroll
    for (int t = 0; t < 4; ++t) {
#pragma unroll
        for (int ks = 0; ks < 4; ++ks) {
            const float* wp = &W[(t * 16 + l16) * IN_DIM + ks * 32 + quad * 8];
            float4 wa = *(const float4*)wp;
            float4 wb = *(const float4*)(wp + 4);
            bfrag[t][ks].u[0] = bf16r(wa.x) | (bf16r(wa.y) << 16);
            bfrag[t][ks].u[1] = bf16r(wa.z) | (bf16r(wa.w) << 16);
            bfrag[t][ks].u[2] = bf16r(wb.x) | (bf16r(wb.y) << 16);
            bfrag[t][ks].u[3] = bf16r(wb.z) | (bf16r(wb.w) << 16);
        }
    }

    if (tile < N_NODES / 16) {
        const int rowbase = tile * 16;
        const float* xrow = &x[(size_t)(rowbase + l16) * IN_DIM];
        f32x4 acc[4] = {{0.f,0.f,0.f,0.f},{0.f,0.f,0.f,0.f},
                        {0.f,0.f,0.f,0.f},{0.f,0.f,0.f,0.f}};
        float ps = 0.f, pd = 0.f;
#pragma unroll
        for (int ks = 0; ks < 4; ++ks) {
            const int k0 = ks * 32 + quad * 8;
            float4 xa = *(const float4*)&xrow[k0];
            float4 xb = *(const float4*)&xrow[k0 + 4];
            ps += xa.x * wsL[k0]     + xa.y * wsL[k0 + 1]
                + xa.z * wsL[k0 + 2] + xa.w * wsL[k0 + 3]
                + xb.x * wsL[k0 + 4] + xb.y * wsL[k0 + 5]
                + xb.z * wsL[k0 + 6] + xb.w * wsL[k0 + 7];
            pd += xa.x * wdL[k0]     + xa.y * wdL[k0 + 1]
                + xa.z * wdL[k0 + 2] + xa.w * wdL[k0 + 3]
                + xb.x * wdL[k0 + 4] + xb.y * wdL[k0 + 5]
                + xb.z * wdL[k0 + 6] + xb.w * wdL[k0 + 7];
            FragU af;
            af.u[0] = bf16r(xa.x) | (bf16r(xa.y) << 16);
            af.u[1] = bf16r(xa.z) | (bf16r(xa.w) << 16);
            af.u[2] = bf16r(xb.x) | (bf16r(xb.y) << 16);
            af.u[3] = bf16r(xb.z) | (bf16r(xb.w) << 16);
#pragma unroll
            for (int t = 0; t < 4; ++t)
                acc[t] = __builtin_amdgcn_mfma_f32_16x16x32_bf16(
                    af.v, bfrag[t][ks].v, acc[t], 0, 0, 0);
        }
        ps += __shfl_xor(ps, 16, 64); ps += __shfl_xor(ps, 32, 64);
        pd += __shfl_xor(pd, 16, 64); pd += __shfl_xor(pd, 32, 64);
        if (quad == 0) { s[rowbase + l16] = ps; d[rowbase + l16] = pd; }
        float* sc = &scratch[wv * 64 * 17];
#pragma unroll
        for (int t = 0; t < 4; ++t)
#pragma unroll
            for (int r = 0; r < 4; ++r)
                sc[(l16 + 16 * t) * 17 + quad * 4 + r] = acc[t][r];
        // same-wave RAW through LDS: compiler inserts lgkmcnt wait
#pragma unroll
        for (int i = 0; i < 2; ++i) {
            int idx = i * 64 + lane;
            int nrow = idx >> 3, q = idx & 7;
            float v0 = sc[(q * 8 + 0) * 17 + nrow];
            float v1 = sc[(q * 8 + 1) * 17 + nrow];
            float v2 = sc[(q * 8 + 2) * 17 + nrow];
            float v3 = sc[(q * 8 + 3) * 17 + nrow];
            float v4 = sc[(q * 8 + 4) * 17 + nrow];
            float v5 = sc[(q * 8 + 5) * 17 + nrow];
            float v6 = sc[(q * 8 + 6) * 17 + nrow];
            float v7 = sc[(q * 8 + 7) * 17 + nrow];
            uint4 o;
            o.x = bf16r(v0) | (bf16r(v1) << 16);
            o.y = bf16r(v2) | (bf16r(v3) << 16);
            o.z = bf16r(v4) | (bf16r(v5) << 16);
            o.w = bf16r(v6) | (bf16r(v7) << 16);
            h4[(size_t)(rowbase + nrow) * 8 + q] = o;
        }
    }
}

// ---------------- scan: exclusive prefix over counts (8 ints/thread) ---------
#define SCAN_V4 (N_NODES / 4)   // 25000 int4 elements
__global__ __launch_bounds__(1024) void k_scan(const int* __restrict__ counts,
                                               int* __restrict__ row_start) {
    __shared__ int wsum[16];
    __shared__ int carry_s;
    const int tid = threadIdx.x;
    const int lane = tid & 63;
    const int wv = tid >> 6;
    if (tid == 0) carry_s = 0;
    __syncthreads();
    for (int base = 0; base < SCAN_V4; base += 2048) {   // 13 chunks
        int i8 = base + tid * 2;
        int4 va = (i8     < SCAN_V4) ? ((const int4*)counts)[i8]     : make_int4(0,0,0,0);
        int4 vb = (i8 + 1 < SCAN_V4) ? ((const int4*)counts)[i8 + 1] : make_int4(0,0,0,0);
        int t1 = va.x, t2 = t1 + va.y, t3 = t2 + va.z, t4 = t3 + va.w;
        int t5 = t4 + vb.x, t6 = t5 + vb.y, t7 = t6 + vb.z, t8 = t7 + vb.w;
        int sc = t8;
#pragma unroll
        for (int off = 1; off < 64; off <<= 1) {
            int t = __shfl_up(sc, off, 64);
            if (lane >= off) sc += t;
        }
        if (lane == 63) wsum[wv] = sc;
        __syncthreads();
        int wprefix = 0;
#pragma unroll
        for (int w = 0; w < 16; ++w) {
            int t = wsum[w];
            if (w < wv) wprefix += t;
        }
        int excl = carry_s + wprefix + (sc - t8);
        if (i8 < SCAN_V4)
            ((int4*)row_start)[i8] = make_int4(excl, excl + t1, excl + t2, excl + t3);
        if (i8 + 1 < SCAN_V4)
            ((int4*)row_start)[i8 + 1] = make_int4(excl + t4, excl + t5, excl + t6, excl + t7);
        __syncthreads();
        if (tid == 0) {
            int tot = 0;
#pragma unroll
            for (int w = 0; w < 16; ++w) tot += wsum[w];
            carry_s += tot;
        }
        __syncthreads();
    }
    if (tid == 0) row_start[N_NODES] = carry_s;
}

// ---------------- K2b: edge attention + atomic-free CSR scatter --------------
__global__ __launch_bounds__(256) void k2b_scatter(const int* __restrict__ ei,
                                                   const float* __restrict__ s,
                                                   const float* __restrict__ d,
                                                   const int* __restrict__ row_start,
                                                   const int* __restrict__ rank,
                                                   uint2* __restrict__ sorted) {
    int i = blockIdx.x * 256 + threadIdx.x;  // grid 6250 exact
    int srcv = ei[i];
    int dstv = ei[N_EDGES + i];
    float e = s[srcv] + d[dstv];
    e = (e > 0.f) ? e : 0.2f * e;            // leaky_relu(0.2)
    float ex = __expf(e);                    // shift-invariant: no global max needed
    int pos = row_start[dstv] + rank[i];
    sorted[pos] = make_uint2((unsigned)srcv, __float_as_uint(ex));
}

// ---------------- K3: aggregation only (bf16 gather, 8-lane edge groups) -----
__global__ __launch_bounds__(256) void k3_agg(const uint2* __restrict__ sorted,
                                              const int* __restrict__ row_start,
                                              const uint4* __restrict__ h4,
                                              uint4* __restrict__ zp) {
    const int lane = threadIdx.x & 63;
    const int node = blockIdx.x * 4 + (threadIdx.x >> 6);  // grid 25000 exact
    const int l8 = lane & 7;
    const int grp = lane >> 3;
    const int beg = row_start[node];
    const int end = row_start[node + 1];
    float a0 = 0.f, a1 = 0.f, a2 = 0.f, a3 = 0.f;
    float a4 = 0.f, a5 = 0.f, a6 = 0.f, a7 = 0.f, se = 0.f;
    int j = beg + grp;
    for (; j + 8 < end; j += 16) {
        uint2 r0 = sorted[j];
        uint2 r1 = sorted[j + 8];
        uint4 g0 = h4[r0.x * 8u + l8];
        uint4 g1 = h4[r1.x * 8u + l8];
        float e0 = __uint_as_float(r0.y), e1 = __uint_as_float(r1.y);
        se += e0 + e1;
        a0 += e0 * blo(g0.x) + e1 * blo(g1.x);
        a1 += e0 * bhi(g0.x) + e1 * bhi(g1.x);
        a2 += e0 * blo(g0.y) + e1 * blo(g1.y);
        a3 += e0 * bhi(g0.y) + e1 * bhi(g1.y);
        a4 += e0 * blo(g0.z) + e1 * blo(g1.z);
        a5 += e0 * bhi(g0.z) + e1 * bhi(g1.z);
        a6 += e0 * blo(g0.w) + e1 * blo(g1.w);
        a7 += e0 * bhi(g0.w) + e1 * bhi(g1.w);
    }
    if (j < end) {   // at most one tail edge per group
        uint2 r = sorted[j];
        uint4 g = h4[r.x * 8u + l8];
        float e = __uint_as_float(r.y);
        se += e;
        a0 += e * blo(g.x); a1 += e * bhi(g.x);
        a2 += e * blo(g.y); a3 += e * bhi(g.y);
        a4 += e * blo(g.z); a5 += e * bhi(g.z);
        a6 += e * blo(g.w); a7 += e * bhi(g.w);
    }
#pragma unroll
    for (int off = 8; off <= 32; off <<= 1) {
        a0 += __shfl_xor(a0, off, 64); a1 += __shfl_xor(a1, off, 64);
        a2 += __shfl_xor(a2, off, 64); a3 += __shfl_xor(a3, off, 64);
        a4 += __shfl_xor(a4, off, 64); a5 += __shfl_xor(a5, off, 64);
        a6 += __shfl_xor(a6, off, 64); a7 += __shfl_xor(a7, off, 64);
        se += __shfl_xor(se, off, 64);
    }
    if (grp == 0) {
        float inv = 1.f / (se + 1e-9f);
        uint4 o;
        o.x = bf16r(fmaxf(a0 * inv, 0.f)) | (bf16r(fmaxf(a1 * inv, 0.f)) << 16);
        o.y = bf16r(fmaxf(a2 * inv, 0.f)) | (bf16r(fmaxf(a3 * inv, 0.f)) << 16);
        o.z = bf16r(fmaxf(a4 * inv, 0.f)) | (bf16r(fmaxf(a5 * inv, 0.f)) << 16);
        o.w = bf16r(fmaxf(a6 * inv, 0.f)) | (bf16r(fmaxf(a7 * inv, 0.f)) << 16);
        zp[node * 8 + l8] = o;   // relu'd, normalized, bf16x8
    }
}

// ---------------- K4: out = z @ W_out^T + b_out (reg-tiled GEMM) -------------
#define K4_M 128
#define ZPAD 133
#define WPAD4 68

__global__ __launch_bounds__(256) void k4_out(const uint2* __restrict__ zp2,
                                              const float* __restrict__ W_out,
                                              const float* __restrict__ b_out,
                                              float* __restrict__ out) {
    __shared__ float zsT[HID * ZPAD];     // [k][m]
    __shared__ float wsT[HID * WPAD4];    // [k][c]
    const int tid = threadIdx.x;
    const int m0g = blockIdx.x * K4_M;    // grid 782, last block partial
    for (int i = tid; i < OUT_DIM * HID; i += 256) {
        int c = i >> 6, k = i & 63;
        wsT[k * WPAD4 + c] = W_out[i];
    }
    for (int i = tid; i < K4_M * 16; i += 256) {   // unpack bf16 z -> fp32 zsT
        int m = i >> 4, q = i & 15;
        int row = m0g + m;
        uint2 v = (row < N_NODES) ? zp2[row * 16 + q] : make_uint2(0u, 0u);
        int kb = q * 4;
        zsT[(kb + 0) * ZPAD + m] = blo(v.x);
        zsT[(kb + 1) * ZPAD + m] = bhi(v.x);
        zsT[(kb + 2) * ZPAD + m] = blo(v.y);
        zsT[(kb + 3) * ZPAD + m] = bhi(v.y);
    }
    __syncthreads();
    const int m0 = (tid & 31) * 4;
    const int c0 = (tid >> 5) * 8;
    float acc[4][8] = {};
#pragma unroll 4
    for (int k = 0; k < HID; ++k) {
        const float4 zv = *(const float4*)&zsT[k * ZPAD + m0];
        const float4 wa = *(const float4*)&wsT[k * WPAD4 + c0];
        const float4 wb = *(const float4*)&wsT[k * WPAD4 + c0 + 4];
#pragma unroll
        for (int i2 = 0; i2 < 4; ++i2) {
            float zi = (&zv.x)[i2];
            acc[i2][0] += zi * wa.x; acc[i2][1] += zi * wa.y;
            acc[i2][2] += zi * wa.z; acc[i2][3] += zi * wa.w;
            acc[i2][4] += zi * wb.x; acc[i2][5] += zi * wb.y;
            acc[i2][6] += zi * wb.z; acc[i2][7] += zi * wb.w;
        }
    }
    const float4 b0 = *(const float4*)&b_out[c0];
    const float4 b1 = *(const float4*)&b_out[c0 + 4];
#pragma unroll
    for (int i2 = 0; i2 < 4; ++i2) {
        int row = m0g + m0 + i2;
        if (row < N_NODES) {
            *(float4*)&out[row * OUT_DIM + c0] =
                make_float4(acc[i2][0] + b0.x, acc[i2][1] + b0.y,
                            acc[i2][2] + b0.z, acc[i2][3] + b0.w);
            *(float4*)&out[row * OUT_DIM + c0 + 4] =
                make_float4(acc[i2][4] + b1.x, acc[i2][5] + b1.y,
                            acc[i2][6] + b1.z, acc[i2][7] + b1.w);
        }
    }
}

extern "C" void kernel_launch(void* const* d_in, const int* in_sizes, int n_in,
                              void* d_out, int out_size, void* d_ws, size_t ws_size,
                              hipStream_t stream) {
    const float* x     = (const float*)d_in[0];
    const int*   ei    = (const int*)d_in[1];
    const float* W_lin = (const float*)d_in[2];
    const float* att   = (const float*)d_in[3];
    const float* W_out = (const float*)d_in[4];
    const float* b_out = (const float*)d_in[5];
    float* out = (float*)d_out;

    // workspace layout (~40.4 MB). rank aliases zp (disjoint lifetimes).
    char* ws = (char*)d_ws;
    unsigned* h2        = (unsigned*)(ws);                    // 12,800,000 B (bf16 h)
    float*    s         = (float*)(ws + 12800000);            //    400,000 B
    float*    d         = (float*)(ws + 13200000);            //    400,000 B
    int*      counts    = (int*)  (ws + 13600000);            //    400,000 B
    int*      row_start = (int*)  (ws + 14000000);            //    400,016 B
    uint2*    sorted    = (uint2*)(ws + 14800016);            // 12,800,000 B
    unsigned* zp        = (unsigned*)(ws + 27600016);         // 12,800,000 B (bf16 z)
    int*      rank      = (int*)zp;                           //  6,400,000 B (alias)

    hipMemsetAsync(counts, 0, N_NODES * sizeof(int), stream);

    k1_k2a<<<K1_BLOCKS + K2A_BLOCKS, 256, 0, stream>>>(
        x, W_lin, att, (uint4*)h2, s, d, ei, counts, rank);
    k_scan<<<1, 1024, 0, stream>>>(counts, row_start);
    k2b_scatter<<<N_EDGES / 256, 256, 0, stream>>>(ei, s, d, row_start, rank, sorted);
    k3_agg<<<N_NODES / 4, 256, 0, stream>>>(sorted, row_start, (const uint4*)h2, (uint4*)zp);
    k4_out<<<(N_NODES + K4_M - 1) / K4_M, 256, 0, stream>>>(
        (const uint2*)zp, W_out, b_out, out);
}